// Round 4
// baseline (207.597 us; speedup 1.0000x reference)
//
#include <hip/hip_runtime.h>
#include <math.h>

typedef unsigned long long u64;
typedef unsigned int u32;

#define BB 8
#define NN 4096
#define MAXK 16
#define BQ 64          // one wave per block
#define BUFSLOTS 16    // per-lane LDS append buffer (8 KB/block)
#define UNROLL 8       // candidates per flush-check; trigger at cnt > 8

// ---- branch-free in-register top-16 machinery (u64 keys, ascending) ----

__device__ __forceinline__ void bitonic16(u64 v[MAXK]) {
#pragma unroll
    for (int k = 2; k <= 16; k <<= 1) {
#pragma unroll
        for (int j = k >> 1; j > 0; j >>= 1) {
#pragma unroll
            for (int i = 0; i < 16; ++i) {
                const int l = i ^ j;
                if (l > i) {
                    const u64 a = v[i], b = v[l];
                    const bool up = ((i & k) == 0);
                    const bool sw = up ? (a > b) : (a < b);
                    v[i] = sw ? b : a;
                    v[l] = sw ? a : b;
                }
            }
        }
    }
}

// list asc + br asc -> list = 16 smallest of the union, ascending.
__device__ __forceinline__ void merge16(u64 list[MAXK], const u64 br[MAXK]) {
    u64 lo[MAXK];
#pragma unroll
    for (int i = 0; i < 16; ++i) {
        const u64 a = list[i], b = br[15 - i];
        lo[i] = a < b ? a : b;              // lower half of bitonic(32)
    }
#pragma unroll
    for (int j = 8; j > 0; j >>= 1) {       // bitonic clean, ascending
#pragma unroll
        for (int i = 0; i < 16; ++i) {
            const int l = i ^ j;
            if (l > i) {
                const u64 a = lo[i], b = lo[l];
                const bool sw = a > b;
                lo[i] = sw ? b : a;
                lo[l] = sw ? a : b;
            }
        }
    }
#pragma unroll
    for (int i = 0; i < 16; ++i) list[i] = lo[i];
}

__device__ __forceinline__ void flush_buf(u64 list[MAXK], u64& wkey, int& cnt,
                                          const u64 (*buf)[BQ], int lane) {
    u64 br[MAXK];
#pragma unroll
    for (int i = 0; i < 16; ++i) {
        const u64 v = buf[i][lane];
        br[i] = (i < cnt) ? v : ~0ull;
    }
    bitonic16(br);
    merge16(list, br);
    wkey = list[15];
    cnt = 0;
}

// k = argmax(kvec)+1 (first index wins), gather preds of selected, mean.
__device__ __forceinline__ void write_mean(const float* __restrict__ pb,
                                           const float* __restrict__ kvec,
                                           const u64 list[MAXK],
                                           float* __restrict__ op) {
    float bv = kvec[0]; int bi = 0;
#pragma unroll
    for (int i = 1; i < MAXK; ++i) { const float v = kvec[i]; if (v > bv) { bv = v; bi = i; } }
    const int k = bi + 1;
    float sx = 0.f, sy = 0.f, sz = 0.f;
#pragma unroll
    for (int s = 0; s < MAXK; ++s) {
        if (s < k) {
            const int j = (int)(u32)list[s];
            sx = __fadd_rn(sx, pb[j * 3 + 0]);
            sy = __fadd_rn(sy, pb[j * 3 + 1]);
            sz = __fadd_rn(sz, pb[j * 3 + 2]);
        }
    }
    const float fk = (float)k;
    op[0] = __fdiv_rn(sx, fk);
    op[1] = __fdiv_rn(sy, fk);
    op[2] = __fdiv_rn(sz, fk);
}

// Precompute (2x, 2y, 2z, ||p||^2). sq uses ORIGINAL coords in reference op
// order. Doubling candidate coords is exact and distributes exactly over fp
// adds, so inner2 == fl(2*inner) bit-for-bit.
__global__ __launch_bounds__(256) void knn_prep(const float* __restrict__ x,
                                                float4* __restrict__ tab) {
    const int i = blockIdx.x * 256 + (int)threadIdx.x;   // 0 .. B*N-1
    const float cx = x[i * 3 + 0], cy = x[i * 3 + 1], cz = x[i * 3 + 2];
    const float sq = __fadd_rn(__fadd_rn(__fmul_rn(cx, cx), __fmul_rn(cy, cy)),
                               __fmul_rn(cz, cz));
    tab[i] = make_float4(__fadd_rn(cx, cx), __fadd_rn(cy, cy),
                         __fadd_rn(cz, cz), sq);
}

template <int SEGS, bool TAB, bool FUSED>
__global__ __launch_bounds__(BQ) void knn_scan(
    const float* __restrict__ x, const float* __restrict__ preds,
    const float* __restrict__ kvec, const float4* __restrict__ tab,
    u64* __restrict__ wkeys, float* __restrict__ out)
{
    constexpr int SEGLEN = NN / SEGS;
    int bid = blockIdx.x;
    const int seg = bid % SEGS;
    bid /= SEGS;
    const int qg = bid % (NN / BQ);
    const int b  = bid / (NN / BQ);
    const int lane = (int)threadIdx.x;
    const int qi = qg * BQ + lane;

    const float* xb = x + (size_t)b * NN * 3;
    const float4* tb = TAB ? (tab + (size_t)b * NN) : nullptr;

    float qx, qy, qz, qsq;
    if (TAB) {
        const float4 qv = tb[qi];                 // (2x,2y,2z,sq)
        qx = __fmul_rn(0.5f, qv.x);               // exact
        qy = __fmul_rn(0.5f, qv.y);
        qz = __fmul_rn(0.5f, qv.z);
        qsq = qv.w;
    } else {
        qx = xb[qi * 3 + 0]; qy = xb[qi * 3 + 1]; qz = xb[qi * 3 + 2];
        qsq = __fadd_rn(__fadd_rn(__fmul_rn(qx, qx), __fmul_rn(qy, qy)),
                        __fmul_rn(qz, qz));
    }

    __shared__ u64 buf[BUFSLOTS][BQ];    // [slot][lane] -> 2-way banks (free)

    u64 list[MAXK];
#pragma unroll
    for (int s = 0; s < MAXK; ++s) list[s] = ~0ull;
    u64 wkey = ~0ull;
    int cnt = 0;

    const int jbase = seg * SEGLEN;
#pragma unroll 1
    for (int t = 0; t < SEGLEN; t += UNROLL) {
        // Room check for the next UNROLL appends; flush is wave-uniform.
        if (__any((int)(cnt > BUFSLOTS - UNROLL))) flush_buf(list, wkey, cnt, buf, lane);
#pragma unroll
        for (int u = 0; u < UNROLL; ++u) {
            const int j = jbase + t + u;            // wave-uniform address
            float c2x, c2y, c2z, csq;
            if (TAB) {
                const float4 c = tb[j];
                c2x = c.x; c2y = c.y; c2z = c.z; csq = c.w;
            } else {
                const float cx = xb[j * 3 + 0], cy = xb[j * 3 + 1], cz = xb[j * 3 + 2];
                csq = __fadd_rn(__fadd_rn(__fmul_rn(cx, cx), __fmul_rn(cy, cy)),
                                __fmul_rn(cz, cz));
                c2x = __fadd_rn(cx, cx); c2y = __fadd_rn(cy, cy); c2z = __fadd_rn(cz, cz);
            }
            // inner2 == 2*inner exactly; d2 bit-identical to reference.
            const float inner2 = __fadd_rn(
                __fadd_rn(__fmul_rn(qx, c2x), __fmul_rn(qy, c2y)),
                __fmul_rn(qz, c2z));
            float d2 = __fsub_rn(__fadd_rn(qsq, csq), inner2);
            d2 = fmaxf(d2, 0.0f);
            const u64 key = ((u64)__float_as_uint(d2) << 32) | (u32)j;
            buf[cnt][lane] = key;                   // unconditional append write
            cnt += (key < wkey) ? 1 : 0;
        }
    }
    flush_buf(list, wkey, cnt, buf, lane);

    if (FUSED) {
        write_mean(preds + (size_t)b * NN * 3, kvec, list,
                   out + ((size_t)b * NN + qi) * 3);
    } else {
        const size_t q = (size_t)b * NN + qi;
#pragma unroll
        for (int s = 0; s < MAXK; ++s)
            wkeys[(size_t)(seg * MAXK + s) * (BB * NN) + q] = list[s];
    }
}

// Tree-merge: the SEGS per-query rows are already sorted ascending lists,
// so just merge16 them pairwise into a running list.
template <int SEGS>
__global__ __launch_bounds__(256) void knn_merge(
    const float* __restrict__ preds, const float* __restrict__ kvec,
    const u64* __restrict__ wkeys, float* __restrict__ out)
{
    const int q = blockIdx.x * 256 + (int)threadIdx.x;  // 0 .. B*N-1

    u64 list[MAXK];
#pragma unroll
    for (int s = 0; s < MAXK; ++s)
        list[s] = wkeys[(size_t)s * (BB * NN) + q];      // coalesced

#pragma unroll 1
    for (int g = 1; g < SEGS; ++g) {
        u64 br[MAXK];
#pragma unroll
        for (int s = 0; s < MAXK; ++s)
            br[s] = wkeys[(size_t)(g * MAXK + s) * (BB * NN) + q];
        merge16(list, br);
    }

    const int b = q / NN;
    write_mean(preds + (size_t)b * NN * 3, kvec, list, out + (size_t)q * 3);
}

extern "C" void kernel_launch(void* const* d_in, const int* in_sizes, int n_in,
                              void* d_out, int out_size, void* d_ws, size_t ws_size,
                              hipStream_t stream) {
    (void)in_sizes; (void)n_in; (void)out_size;
    const float* x     = (const float*)d_in[0];
    const float* preds = (const float*)d_in[1];
    const float* kvec  = (const float*)d_in[2];
    float* out = (float*)d_out;

    const size_t keys16 = 16ull * MAXK * BB * NN * sizeof(u64);  // 64 MiB
    const size_t keys8  =  8ull * MAXK * BB * NN * sizeof(u64);  // 32 MiB
    const size_t keys4  =  4ull * MAXK * BB * NN * sizeof(u64);  // 16 MiB
    const size_t tabsz  = (size_t)BB * NN * sizeof(float4);      // 0.5 MiB

    if (ws_size >= keys16 + tabsz) {
        u64* wkeys  = (u64*)d_ws;
        float4* tab = (float4*)((char*)d_ws + keys16);
        knn_prep<<<(BB * NN) / 256, 256, 0, stream>>>(x, tab);
        knn_scan<16, true, false><<<BB * (NN / BQ) * 16, BQ, 0, stream>>>(
            x, preds, kvec, tab, wkeys, out);
        knn_merge<16><<<(BB * NN) / 256, 256, 0, stream>>>(preds, kvec, wkeys, out);
    } else if (ws_size >= keys8 + tabsz) {
        u64* wkeys  = (u64*)d_ws;
        float4* tab = (float4*)((char*)d_ws + keys8);
        knn_prep<<<(BB * NN) / 256, 256, 0, stream>>>(x, tab);
        knn_scan<8, true, false><<<BB * (NN / BQ) * 8, BQ, 0, stream>>>(
            x, preds, kvec, tab, wkeys, out);
        knn_merge<8><<<(BB * NN) / 256, 256, 0, stream>>>(preds, kvec, wkeys, out);
    } else if (ws_size >= keys4) {
        u64* wkeys = (u64*)d_ws;
        knn_scan<4, false, false><<<BB * (NN / BQ) * 4, BQ, 0, stream>>>(
            x, preds, kvec, nullptr, wkeys, out);
        knn_merge<4><<<(BB * NN) / 256, 256, 0, stream>>>(preds, kvec, wkeys, out);
    } else {
        knn_scan<1, false, true><<<BB * (NN / BQ), BQ, 0, stream>>>(
            x, preds, kvec, nullptr, nullptr, out);
    }
}